// Round 6
// baseline (696.805 us; speedup 1.0000x reference)
//
#include <hip/hip_runtime.h>
#include <math.h>

// GCN 2-layer + pool + head. Destination-bucketed, 4-edges-per-thread,
// LDS accumulators (NATIVE ds_add_f32 via unsafeAtomicAdd — plain float
// atomicAdd on LDS compiles to a CAS retry loop, which pinned gathers at
// 279 us across three structurally different kernels in R3-R5), dinv folded
// into features, bf16 feature tables (3.2 MB -> per-XCD-L2-resident).
//
// Bucket b = v / NPB (NPB=100, NB=1000). Edges partitioned into per-bucket
// segments of capacity CAP, packed = row | (c_local<<17).
//   h0s[v] = bf16( dinv[v]*(x[v]@W1) )
//   layer: acc[c] = sum_{(r->c)} h0s[r];  out = dinv[c]*(acc + h0s[c]) + bias
//
// Workspace: cursor[1024] int | dinv[N] f32 | packed[NB*CAP] int
//            | h0s[16N] bf16 | t2s[16N] bf16 | g[16G] f32   ~= 22.3 MB.

#define NPB     100
#define NBMAX   1024
#define CAP     3840    // mean E/NB = 3200, sigma ~57 -> 11 sigma; CAP%4==0
#define PT_TILE 8192

__device__ __forceinline__ float bf2f_lo(unsigned u) {
    union { unsigned i; float f; } c; c.i = u << 16; return c.f;
}
__device__ __forceinline__ float bf2f_hi(unsigned u) {
    union { unsigned i; float f; } c; c.i = u & 0xFFFF0000u; return c.f;
}
__device__ __forceinline__ unsigned short f2bf(float f) {   // round-nearest-even
    union { float f; unsigned i; } c; c.f = f;
    return (unsigned short)((c.i + 0x7FFFu + ((c.i >> 16) & 1u)) >> 16);
}

__global__ void k_init(int* cursor, float* g, int NB, int G16) {
    int i = blockIdx.x * blockDim.x + threadIdx.x;
    if (i < NB) cursor[i] = i * CAP;
    if (i < G16) g[i] = 0.0f;
}

__global__ __launch_bounds__(512)
void k_partition(const int* __restrict__ row, const int* __restrict__ col,
                 int* cursor, int* __restrict__ packed, int E) {
    __shared__ int hist[NBMAX];
    __shared__ int rstart[NBMAX];
    __shared__ int loff[NBMAX];
    int tid = threadIdx.x;
    for (int b = tid; b < NBMAX; b += 512) hist[b] = 0;
    __syncthreads();
    int e0 = blockIdx.x * PT_TILE;
#pragma unroll
    for (int j = 0; j < PT_TILE / 512; ++j) {
        int e = e0 + tid + j * 512;
        if (e < E) atomicAdd(&hist[col[e] / NPB], 1);
    }
    __syncthreads();
    for (int b = tid; b < NBMAX; b += 512) {
        loff[b] = 0;
        if (hist[b] > 0) rstart[b] = atomicAdd(&cursor[b], hist[b]);
    }
    __syncthreads();
#pragma unroll
    for (int j = 0; j < PT_TILE / 512; ++j) {
        int e = e0 + tid + j * 512;
        if (e < E) {
            int c = col[e];
            int b = c / NPB;
            int rank = atomicAdd(&loff[b], 1);
            packed[rstart[b] + rank] = row[e] | ((c - b * NPB) << 17);
        }
    }
}

// Per-bucket degree (LDS hist) -> dinv, then h0s = bf16(dinv * (x @ W1)).
__global__ __launch_bounds__(512)
void k_deg_xw1(const int* __restrict__ packed, const int* __restrict__ cursor,
               const float* __restrict__ x, const float* __restrict__ W1,
               float* __restrict__ dinv, unsigned short* __restrict__ h0s, int N) {
    __shared__ int   deg[NPB];
    __shared__ float sdinv[NPB];
    __shared__ float sW1[48];
    int b = blockIdx.x, tid = threadIdx.x;
    if (tid < NPB) deg[tid] = 0;
    if (tid < 48) sW1[tid] = W1[tid];
    __syncthreads();
    int s = b * CAP, n = cursor[b] - s;
    for (int i = tid; i < n; i += 512)
        atomicAdd(&deg[((unsigned)packed[s + i]) >> 17], 1);
    __syncthreads();
    int v0 = b * NPB;
    int vcnt = min(NPB, N - v0);
    if (tid < vcnt) {
        float dv = rsqrtf((float)(1 + deg[tid]));   // +1 self-loop
        sdinv[tid] = dv;
        dinv[v0 + tid] = dv;
    }
    __syncthreads();
    for (int i = tid; i < vcnt * 16; i += 512) {
        int vl = i >> 4, k = i & 15, v = v0 + vl;
        float x0 = x[v * 3 + 0], x1 = x[v * 3 + 1], x2 = x[v * 3 + 2];
        h0s[v * 16 + k] = f2bf(sdinv[vl] *
            (x0 * sW1[k] + x1 * sW1[16 + k] + x2 * sW1[32 + k]));
    }
}

// Edge accumulation: 4 edges per thread per sweep. One int4 packed load +
// 8 independent uint4 bf16-row loads in flight, then NATIVE LDS fp atomics.
#define EDGE_ACC_LOOP(SRCB)                                                   \
    for (int base = tid * 4; base < n; base += 2048) {                        \
        int4 pk4 = *(const int4*)(packed + s + base);                         \
        unsigned pk[4] = {(unsigned)pk4.x, (unsigned)pk4.y,                   \
                          (unsigned)pk4.z, (unsigned)pk4.w};                  \
        bool ok[4]; int r[4], cl[4];                                          \
        _Pragma("unroll")                                                     \
        for (int j = 0; j < 4; ++j) {                                         \
            ok[j] = (base + j) < n;                                           \
            r[j]  = ok[j] ? (int)(pk[j] & 0x1FFFFu) : 0;                      \
            cl[j] = ok[j] ? (int)(pk[j] >> 17) : 0;                           \
        }                                                                     \
        uint4 lo[4], hi[4];                                                   \
        _Pragma("unroll")                                                     \
        for (int j = 0; j < 4; ++j) {                                         \
            const uint4* rp = (const uint4*)((SRCB) + r[j] * 16);             \
            lo[j] = rp[0]; hi[j] = rp[1];                                     \
        }                                                                     \
        _Pragma("unroll")                                                     \
        for (int j = 0; j < 4; ++j) {                                         \
            if (!ok[j]) continue;                                             \
            float* ar = acc + cl[j] * 17;                                     \
            unsafeAtomicAdd(ar + 0,  bf2f_lo(lo[j].x));                       \
            unsafeAtomicAdd(ar + 1,  bf2f_hi(lo[j].x));                       \
            unsafeAtomicAdd(ar + 2,  bf2f_lo(lo[j].y));                       \
            unsafeAtomicAdd(ar + 3,  bf2f_hi(lo[j].y));                       \
            unsafeAtomicAdd(ar + 4,  bf2f_lo(lo[j].z));                       \
            unsafeAtomicAdd(ar + 5,  bf2f_hi(lo[j].z));                       \
            unsafeAtomicAdd(ar + 6,  bf2f_lo(lo[j].w));                       \
            unsafeAtomicAdd(ar + 7,  bf2f_hi(lo[j].w));                       \
            unsafeAtomicAdd(ar + 8,  bf2f_lo(hi[j].x));                       \
            unsafeAtomicAdd(ar + 9,  bf2f_hi(hi[j].x));                       \
            unsafeAtomicAdd(ar + 10, bf2f_lo(hi[j].y));                       \
            unsafeAtomicAdd(ar + 11, bf2f_hi(hi[j].y));                       \
            unsafeAtomicAdd(ar + 12, bf2f_lo(hi[j].z));                       \
            unsafeAtomicAdd(ar + 13, bf2f_hi(hi[j].z));                       \
            unsafeAtomicAdd(ar + 14, bf2f_lo(hi[j].w));                       \
            unsafeAtomicAdd(ar + 15, bf2f_hi(hi[j].w));                       \
        }                                                                     \
    }

// Layer 1 fused: msg-sum -> +selfloop +b1 -> relu -> @W2 -> *dinv -> t2s (bf16)
__global__ __launch_bounds__(512)
void k_gather1(const int* __restrict__ packed, const int* __restrict__ cursor,
               const float* __restrict__ dinv, const unsigned short* __restrict__ h0s,
               const float* __restrict__ b1, const float* __restrict__ W2,
               unsigned short* __restrict__ t2s, int N) {
    __shared__ float acc[NPB * 17];
    __shared__ float sW2[256];
    int b = blockIdx.x, tid = threadIdx.x;
    for (int i = tid; i < NPB * 17; i += 512) acc[i] = 0.0f;
    if (tid < 256) sW2[tid] = W2[tid];
    __syncthreads();
    int s = b * CAP, n = cursor[b] - s;
    EDGE_ACC_LOOP(h0s)
    __syncthreads();
    int v0 = b * NPB, vcnt = min(NPB, N - v0);
    for (int i = tid; i < vcnt * 16; i += 512) {
        int vl = i >> 4, k = i & 15, v = v0 + vl;
        float dv = dinv[v];
        float self = bf2f_lo((unsigned)h0s[v * 16 + k]);
        float val = dv * (acc[vl * 17 + k] + self) + b1[k];
        acc[vl * 17 + k] = fmaxf(val, 0.0f);
    }
    __syncthreads();
    for (int i = tid; i < vcnt * 16; i += 512) {
        int vl = i >> 4, kp = i & 15, v = v0 + vl;
        const float* rr = acc + vl * 17;
        float a = 0.0f;
#pragma unroll
        for (int k = 0; k < 16; ++k) a += rr[k] * sW2[k * 16 + kp];
        t2s[v * 16 + kp] = f2bf(dinv[v] * a);
    }
}

// Layer 2 fused: msg-sum -> +selfloop +b2 -> per-graph LDS pool -> global g
__global__ __launch_bounds__(512)
void k_gather2(const int* __restrict__ packed, const int* __restrict__ cursor,
               const float* __restrict__ dinv, const unsigned short* __restrict__ t2s,
               const float* __restrict__ b2, const int* __restrict__ batch,
               float* __restrict__ g, int N) {
    __shared__ float acc[NPB * 17];
    __shared__ float pacc[NPB * 16];
    int b = blockIdx.x, tid = threadIdx.x;
    for (int i = tid; i < NPB * 17; i += 512) acc[i] = 0.0f;
    for (int i = tid; i < NPB * 16; i += 512) pacc[i] = 0.0f;
    __syncthreads();
    int s = b * CAP, n = cursor[b] - s;
    EDGE_ACC_LOOP(t2s)
    __syncthreads();
    int v0 = b * NPB, vcnt = min(NPB, N - v0);
    int b0 = batch[v0];
    for (int i = tid; i < vcnt * 16; i += 512) {
        int vl = i >> 4, k = i & 15, v = v0 + vl;
        float dv = dinv[v];
        float self = bf2f_lo((unsigned)t2s[v * 16 + k]);
        float val = dv * (acc[vl * 17 + k] + self) + b2[k];
        int d = batch[v] - b0;                 // batch sorted
        if (d < NPB) unsafeAtomicAdd(&pacc[d * 16 + k], val);
        else         unsafeAtomicAdd(&g[batch[v] * 16 + k], val);
    }
    __syncthreads();
    int grange = min(batch[v0 + vcnt - 1] - b0 + 1, NPB);
    for (int i = tid; i < grange * 16; i += 512)
        unsafeAtomicAdd(&g[(b0 + (i >> 4)) * 16 + (i & 15)], pacc[i]);
}

// logits = g @ Wl + bl (16x7), log_softmax over 7. One thread per graph.
__global__ void k_head(const float* __restrict__ g, const float* __restrict__ Wl,
                       const float* __restrict__ bl, float* __restrict__ out, int G) {
    int gi = blockIdx.x * blockDim.x + threadIdx.x;
    if (gi >= G) return;
    float gv[16];
#pragma unroll
    for (int kk = 0; kk < 16; ++kk) gv[kk] = g[gi * 16 + kk];
    float lo[7];
    float mx = -1e30f;
#pragma unroll
    for (int j = 0; j < 7; ++j) {
        float a = bl[j];
#pragma unroll
        for (int kk = 0; kk < 16; ++kk) a += gv[kk] * Wl[kk * 7 + j];
        lo[j] = a;
        mx = fmaxf(mx, a);
    }
    float ssum = 0.0f;
#pragma unroll
    for (int j = 0; j < 7; ++j) ssum += expf(lo[j] - mx);
    float lse = mx + logf(ssum);
#pragma unroll
    for (int j = 0; j < 7; ++j) out[gi * 7 + j] = lo[j] - lse;
}

extern "C" void kernel_launch(void* const* d_in, const int* in_sizes, int n_in,
                              void* d_out, int out_size, void* d_ws, size_t ws_size,
                              hipStream_t stream) {
    const float* x     = (const float*)d_in[0];
    const int*   ei    = (const int*)d_in[1];   // row = ei[0:E), col = ei[E:2E)
    const int*   batch = (const int*)d_in[3];
    const float* W1 = (const float*)d_in[4];
    const float* b1 = (const float*)d_in[5];
    const float* W2 = (const float*)d_in[6];
    const float* b2 = (const float*)d_in[7];
    const float* Wl = (const float*)d_in[8];
    const float* bl = (const float*)d_in[9];
    float* out = (float*)d_out;

    const int N = in_sizes[0] / 3;   // 100000 (< 2^17 required by packing)
    const int E = in_sizes[1] / 2;
    const int G = out_size / 7;
    const int NB = (N + NPB - 1) / NPB;   // 1000

    const int* row = ei;
    const int* col = ei + E;

    int*            cursor = (int*)d_ws;                       // NBMAX
    float*          dinv   = (float*)(cursor + NBMAX);         // N
    int*            packed = (int*)(dinv + N);                 // NB*CAP
    unsigned short* h0s    = (unsigned short*)(packed + NB * CAP); // 16N bf16
    unsigned short* t2s    = h0s + 16 * N;                     // 16N bf16
    float*          g      = (float*)(t2s + 16 * N);           // 16G

    const int TB = 256;
    int initN = max(NBMAX, G * 16);

    k_init<<<(initN + TB - 1) / TB, TB, 0, stream>>>(cursor, g, NB, G * 16);
    k_partition<<<(E + PT_TILE - 1) / PT_TILE, 512, 0, stream>>>(row, col, cursor, packed, E);
    k_deg_xw1<<<NB, 512, 0, stream>>>(packed, cursor, x, W1, dinv, h0s, N);
    k_gather1<<<NB, 512, 0, stream>>>(packed, cursor, dinv, h0s, b1, W2, t2s, N);
    k_gather2<<<NB, 512, 0, stream>>>(packed, cursor, dinv, t2s, b2, batch, g, N);
    k_head<<<(G + TB - 1) / TB, TB, 0, stream>>>(g, Wl, bl, out, G);
}